// Round 5
// baseline (603.852 us; speedup 1.0000x reference)
//
#include <hip/hip_runtime.h>
#include <math.h>
#include <limits.h>

#define CAP 64
#define TPB 256
#define RPB 4     // rows per block (one wave each)
#define NMAX 1024

typedef float f4 __attribute__((ext_vector_type(4)));

__device__ inline f4 ntload4(const float* p) { return __builtin_nontemporal_load((const f4*)p); }
__device__ inline void ntstore4(float* p, f4 v) { __builtin_nontemporal_store(v, (f4*)p); }
__device__ inline void ntstore1(float* p, float v) { __builtin_nontemporal_store(v, p); }

__device__ inline float waveSum(float v) {
#pragma unroll
  for (int o = 32; o > 0; o >>= 1) v += __shfl_down(v, o, 64);
  return v;
}

// K1 (fused): per adj row: y-dot, weighted sum, count, compressed nonzero list
// (ballot compaction, no atomics); zeroes colCount/colK/batchDone. Wave per row.
__global__ void k_prep(const float* __restrict__ x, const float* __restrict__ adj,
                       const float* __restrict__ W, float* __restrict__ y,
                       int* __restrict__ rowCnt, int* __restrict__ rowIdx,
                       float* __restrict__ rowVal, float* __restrict__ dis,
                       float* __restrict__ d2, float* __restrict__ wsum,
                       int* __restrict__ colCount, int* __restrict__ colK,
                       int* __restrict__ batchDone,
                       int N, int F, int BN, int B) {
  int wave = threadIdx.x >> 6, lane = threadIdx.x & 63;
  if (blockIdx.x == 0 && threadIdx.x < B) { colK[threadIdx.x] = 0; batchDone[threadIdx.x] = 0; }
  int bn = blockIdx.x * RPB + wave;
  if (bn >= BN) return;
  if (lane == 0) colCount[bn] = 0;
  // ---- y = dot(x[bn,:], W) ----
  float p = 0.f;
  if ((F & 3) == 0) {
    const float* xr = x + (size_t)bn * F;
    int f4n = F >> 2;
    for (int i = lane; i < f4n; i += 64) {
      f4 a = *(const f4*)(xr + 4 * i);
      f4 w = *(const f4*)(W + 4 * i);
      p += a.x * w.x + a.y * w.y + a.z * w.z + a.w * w.w;
    }
  } else {
    for (int f = lane; f < F; f += 64) p += x[(size_t)bn * F + f] * W[f];
  }
  float ydot = waveSum(p);
  // ---- adj row scan: sum + ballot-compacted nonzero list ----
  const float* row = adj + (size_t)bn * N;
  size_t lbase = (size_t)bn * CAP;
  unsigned long long below = (1ULL << lane) - 1ULL;
  float ls = 0.f;
  int cnt = 0;
  if ((N & 3) == 0) {
    int n4 = N >> 2;
    for (int q = lane; q < n4; q += 64) {
      f4 v = ntload4(row + 4 * q);
      ls += v.x + v.y + v.z + v.w;
      int j = q << 2;
#pragma unroll
      for (int c = 0; c < 4; c++) {
        float vc = (c == 0) ? v.x : (c == 1) ? v.y : (c == 2) ? v.z : v.w;
        unsigned long long m = __ballot(vc > 0.f);
        if (vc > 0.f) {
          int pos = cnt + __popcll(m & below);
          if (pos < CAP) { rowIdx[lbase + pos] = j + c; rowVal[lbase + pos] = vc; }
        }
        cnt += __popcll(m);
      }
    }
  } else {
    for (int j = lane; j < N; j += 64) {
      float v = row[j];
      ls += v;
      unsigned long long m = __ballot(v > 0.f);
      if (v > 0.f) {
        int pos = cnt + __popcll(m & below);
        if (pos < CAP) { rowIdx[lbase + pos] = j; rowVal[lbase + pos] = v; }
      }
      cnt += __popcll(m);
    }
  }
  float s = waveSum(ls);
  if (lane == 0) {
    y[bn] = ydot;
    rowCnt[bn] = cnt;                          // lane 0 runs max iterations -> full count
    dis[bn] = 1.f / sqrtf((float)(cnt + 1));   // A_hat row sum = count + 1 (self loop)
    wsum[bn] = s;
    d2[bn] = 1.f / sqrtf(fmaxf(s + 1.f, 1.f)); // clip(A2.sum,1)^-0.5
  }
}

// K2 (fused alpha + cut): wave-per-row alpha; last block of each batch runs
// the top-k cut inline (device-scope fence + atomic completion counter).
__global__ void k_alpha_cut(const float* __restrict__ adj, const int* __restrict__ rowCnt,
                            const int* __restrict__ rowIdx, const float* __restrict__ dis,
                            const float* __restrict__ y, const float* __restrict__ bptr,
                            const int* __restrict__ num_nodes,
                            const int* __restrict__ num_sentences,
                            const int* __restrict__ kptr,
                            float* __restrict__ alpha, float* __restrict__ cutA,
                            float* __restrict__ outIM, int* __restrict__ colK,
                            int* __restrict__ colIdx, int* __restrict__ batchDone,
                            int N, int BN) {
  int wave = threadIdx.x >> 6, lane = threadIdx.x & 63;
  int bn = blockIdx.x * RPB + wave;
  if (bn < BN) {
    int b = bn / N, n = bn - b * N;
    const float* disB = dis + (size_t)b * N;
    const float* yB = y + (size_t)b * N;
    int cnt = rowCnt[bn];
    float acc = 0.f;
    if (cnt <= CAP) {
      for (int t = lane; t < cnt; t += 64) {
        int j = rowIdx[(size_t)bn * CAP + t];
        acc += disB[j] * yB[j];
      }
    } else {
      const float* row = adj + (size_t)bn * N;
      for (int j = lane; j < N; j += 64)
        if (row[j] > 0.f) acc += disB[j] * yB[j];
    }
    float tot = waveSum(acc);
    if (lane == 0) {
      float dn = dis[bn];
      tot += dn * yB[n];                 // self-loop term
      float z = dn * tot + bptr[0];
      float a;
      if (n < num_nodes[b]) { float z2 = z * z; a = 1.f / (1.f + expf(-z2)); }
      else a = -1.f;
      alpha[bn] = a;
    }
  }
  // ---- completion accounting: block's rows -> per-batch counters ----
  __shared__ int winB[2];
  __syncthreads();                // all block's alpha stores complete (to L2)
  if (threadIdx.x == 0) {
    winB[0] = winB[1] = -1;
    int start = blockIdx.x * RPB;
    int end = start + RPB; if (end > BN) end = BN;
    int i = start, w = 0;
    __threadfence();              // agent release: flush this XCD's L2
    while (i < end) {
      int b = i / N;
      int segEnd = (b + 1) * N; if (segEnd > end) segEnd = end;
      int c = segEnd - i;
      int old = atomicAdd(&batchDone[b], c);
      if (old + c == N && w < 2) winB[w++] = b;
      i = segEnd;
    }
  }
  __syncthreads();
#pragma unroll
  for (int w = 0; w < 2; w++) {
    int b = winB[w];
    if (b < 0) continue;
    __threadfence();              // agent acquire: invalidate stale caches
    const float* aB = alpha + (size_t)b * N;
    __shared__ float s_cutv;
    __shared__ int s_cutn;
    if (threadIdx.x < 64) {
      int ln = threadIdx.x;
      int ns = num_sentences[b];
      int k = kptr[0];
      if (k < 1) k = 1;
      if (k > ns) k = ns;
      unsigned long long used = 0ULL;
      float cv = 0.f; int cn = 0;
      int nslots = (ns + 63) >> 6;
      for (int r = 0; r < k; r++) {
        float bv = -3.4e38f; int bi = INT_MAX;
        for (int s = 0; s < nslots; s++) {
          int idx = ln + (s << 6);
          if (idx < ns && !((used >> s) & 1ULL)) {
            float v = aB[idx];
            if (v > bv || (v == bv && idx < bi)) { bv = v; bi = idx; }
          }
        }
#pragma unroll
        for (int o = 32; o > 0; o >>= 1) {
          float ov = __shfl_down(bv, o, 64);
          int oi = __shfl_down(bi, o, 64);
          if (ov > bv || (ov == bv && oi < bi)) { bv = ov; bi = oi; }
        }
        bv = __shfl(bv, 0, 64);
        bi = __shfl(bi, 0, 64);
        if ((bi & 63) == ln) used |= 1ULL << (bi >> 6);
        cv = bv; cn = bi;
      }
      if (ln == 0) { s_cutv = cv; s_cutn = cn; }
    }
    __syncthreads();
    float cutv = s_cutv;
    int cutn = s_cutn;
    for (int n = threadIdx.x; n < N; n += TPB) {
      float a = aB[n];
      float ca = fmaxf((a + 1e-7f) - cutv, 0.f);
      cutA[(size_t)b * N + n] = ca;
      ntstore1(&outIM[(size_t)b * N + n], (a > cutv || (a == cutv && n <= cutn)) ? 1.f : 0.f);
      if (ca > 0.f) {
        int p = atomicAdd(&colK[b], 1);
        colIdx[(size_t)b * N + p] = n;
      }
    }
    __syncthreads();
  }
}

// K3: S rows — wave per row. Scatter into LDS row, dense nt write, build CSC.
__global__ void k_srow(const float* __restrict__ adj, const int* __restrict__ rowCnt,
                       const int* __restrict__ rowIdx, const float* __restrict__ rowVal,
                       const float* __restrict__ wsum, const float* __restrict__ d2,
                       const float* __restrict__ cutA, float* __restrict__ outS,
                       int* __restrict__ colCount, int* __restrict__ colR,
                       float* __restrict__ colV, int N, int BN) {
  int wave = threadIdx.x >> 6, lane = threadIdx.x & 63;
  int bn = blockIdx.x * RPB + wave;
  bool rowOK = bn < BN;
  __shared__ float srow[RPB][NMAX];
  float* my = srow[wave];
  if (rowOK) {
    f4 z4 = { 0.f, 0.f, 0.f, 0.f };
    int nq = N >> 2;
    for (int q = lane; q < nq; q += 64) *(f4*)&my[4 * q] = z4;
    for (int j = (nq << 2) + lane; j < N; j += 64) my[j] = 0.f;
  }
  if (rowOK && wsum[bn] > 0.f) {
    int b = bn / N, n = bn - b * N;
    int cnt = rowCnt[bn];
    const float* d2B = d2 + (size_t)b * N;
    const float* caB = cutA + (size_t)b * N;
    float d2n = d2[bn];
    if (cnt < CAP) {
      int t = lane;
      int j = -1; float a2 = 0.f;
      if (t < cnt) {
        j = rowIdx[(size_t)bn * CAP + t];
        float v = rowVal[(size_t)bn * CAP + t];
        a2 = v + (j == n ? 1.f : 0.f);
      }
      unsigned long long hasDiag = __ballot(t < cnt && j == n);
      if (t == cnt && hasDiag == 0ULL) { j = n; a2 = 1.f; }
      float sun = 0.f;
      if (j >= 0) {
        float ca = caB[j];
        if (ca > 0.f) sun = d2n * a2 * d2B[j] * ca;
        else j = -1;
      }
      float denom = __shfl(waveSum(sun), 0, 64);
      denom = fmaxf(denom, 1e-12f);
      if (j >= 0) {
        float s = sun / denom;
        my[j] = s;
        int cp = atomicAdd(&colCount[(size_t)b * N + j], 1);
        if (cp < CAP) {
          colR[((size_t)b * N + j) * CAP + cp] = n;
          colV[((size_t)b * N + j) * CAP + cp] = s;
        }
      }
    } else {
      // dense fallback (statistically never taken)
      const float* row = adj + (size_t)bn * N;
      float ls = 0.f;
      for (int j2 = lane; j2 < N; j2 += 64) {
        float v = row[j2];
        bool nz = (v > 0.f) || (j2 == n);
        float a2 = v + (j2 == n ? 1.f : 0.f);
        float ca = caB[j2];
        if (nz && ca > 0.f) ls += d2n * a2 * d2B[j2] * ca;
      }
      float denom = __shfl(waveSum(ls), 0, 64);
      denom = fmaxf(denom, 1e-12f);
      for (int j2 = lane; j2 < N; j2 += 64) {
        float v = row[j2];
        bool nz = (v > 0.f) || (j2 == n);
        float a2 = v + (j2 == n ? 1.f : 0.f);
        float ca = caB[j2];
        if (nz && ca > 0.f) {
          float s = (d2n * a2 * d2B[j2] * ca) / denom;
          my[j2] = s;
          int cp = atomicAdd(&colCount[(size_t)b * N + j2], 1);
          if (cp < CAP) {
            colR[((size_t)b * N + j2) * CAP + cp] = n;
            colV[((size_t)b * N + j2) * CAP + cp] = s;
          }
        }
      }
    }
  }
  if (rowOK) {
    float* dst = outS + (size_t)bn * N;
    if ((N & 3) == 0) {
      int nq = N >> 2;
      for (int q = lane; q < nq; q += 64) ntstore4(dst + 4 * q, *(const f4*)&my[4 * q]);
    } else {
      for (int j = lane; j < N; j += 64) ntstore1(&dst[j], my[j]);
    }
  }
}

// K4: x_c rows (S^T x) and coarse_adj rows (S^T A S with floor) — list-based
__global__ void k_coarse(const float* __restrict__ adj, const float* __restrict__ x,
                         const float* __restrict__ cutA,
                         const int* __restrict__ rowCnt, const int* __restrict__ rowIdx,
                         const float* __restrict__ rowVal,
                         const int* __restrict__ colK, const int* __restrict__ colIdx,
                         const int* __restrict__ colCount, const int* __restrict__ colR,
                         const float* __restrict__ colV,
                         float* __restrict__ outXc, float* __restrict__ outC,
                         int N, int F) {
  int bn = blockIdx.x;
  int b = bn / N;
  float* xcRow = outXc + (size_t)bn * F;
  float* cRow = outC + (size_t)bn * N;
  bool v4N = (N & 3) == 0, v4F = (F & 3) == 0;
  int nq = N >> 2, fq = F >> 2;
  if (cutA[bn] <= 0.f) {
    f4 z4 = { 0.f, 0.f, 0.f, 0.f };
    if (v4F) for (int q = threadIdx.x; q < fq; q += TPB) ntstore4(xcRow + 4 * q, z4);
    else for (int f = threadIdx.x; f < F; f += TPB) ntstore1(&xcRow[f], 0.f);
    if (v4N) for (int q = threadIdx.x; q < nq; q += TPB) ntstore4(cRow + 4 * q, z4);
    else for (int j = threadIdx.x; j < N; j += TPB) ntstore1(&cRow[j], 0.f);
    return;
  }
  __shared__ float T[NMAX];
  __shared__ float crow[NMAX];
  __shared__ int eR[CAP];
  __shared__ float eV[CAP];
  __shared__ int eCnt[CAP];
  int cci = colCount[bn];
  if (cci > CAP) cci = CAP;
  for (int r = threadIdx.x; r < cci; r += TPB) {
    int n_r = colR[(size_t)bn * CAP + r];
    eR[r] = n_r;
    eV[r] = colV[(size_t)bn * CAP + r];
    eCnt[r] = rowCnt[(size_t)b * N + n_r];
  }
  for (int m = threadIdx.x; m < N; m += TPB) { T[m] = 0.f; crow[m] = 0.f; }
  __syncthreads();
  // x_c row: gather over the cci source rows of x
  const float* xB = x + (size_t)b * N * F;
  for (int f = threadIdx.x; f < F; f += TPB) {
    float acc = 0.f;
    for (int r = 0; r < cci; r++) acc += eV[r] * xB[(size_t)eR[r] * F + f];
    ntstore1(&xcRow[f], acc);
  }
  // T = sum_r v_r * adj[n_r,:] via compressed row lists (LDS float atomics)
  for (int idx = threadIdx.x; idx < cci * CAP; idx += TPB) {
    int r = idx >> 6;          // CAP == 64
    int t = idx & (CAP - 1);
    int c = eCnt[r];
    if (c <= CAP && t < c) {
      size_t base = ((size_t)b * N + eR[r]) * CAP;
      atomicAdd(&T[rowIdx[base + t]], eV[r] * rowVal[base + t]);
    }
  }
  // rare fallback: rows whose nonzero count exceeded CAP — stream from adj
  for (int r = 0; r < cci; r++) {
    if (eCnt[r] > CAP) {
      const float* arow = adj + ((size_t)b * N + eR[r]) * N;
      float v = eV[r];
      for (int m = threadIdx.x; m < N; m += TPB) {
        float a = arow[m];
        if (a != 0.f) atomicAdd(&T[m], v * a);
      }
    }
  }
  __syncthreads();
  // C[i,j] for the nonzero columns j via CSC lists
  int K = colK[b];
  for (int jj = threadIdx.x; jj < K; jj += TPB) {
    int j = colIdx[(size_t)b * N + jj];
    int cj = colCount[(size_t)b * N + j];
    if (cj > CAP) cj = CAP;
    const int* jR = colR + ((size_t)b * N + j) * CAP;
    const float* jV = colV + ((size_t)b * N + j) * CAP;
    float cc = 0.f;
    for (int p = 0; p < cj; p++) cc += T[jR[p]] * jV[p];
    crow[j] = floorf(cc * 1e4f) / 1e4f;
  }
  __syncthreads();
  if (v4N) {
    for (int q = threadIdx.x; q < nq; q += TPB) ntstore4(cRow + 4 * q, *(const f4*)&crow[4 * q]);
  } else {
    for (int j = threadIdx.x; j < N; j += TPB) ntstore1(&cRow[j], crow[j]);
  }
}

extern "C" void kernel_launch(void* const* d_in, const int* in_sizes, int n_in,
                              void* d_out, int out_size, void* d_ws, size_t ws_size,
                              hipStream_t stream) {
  const float* x = (const float*)d_in[0];
  const float* adj = (const float*)d_in[1];
  const float* W = (const float*)d_in[2];
  const float* bias = (const float*)d_in[3];
  const int* num_nodes = (const int*)d_in[4];
  const int* num_sentences = (const int*)d_in[5];
  const int* kptr = (const int*)d_in[6];

  int F = in_sizes[2];                             // 256
  int B = in_sizes[4];                             // 32
  int N = (int)(in_sizes[0] / ((long long)B * F)); // 1000
  size_t BN = (size_t)B * N;

  float* outXc = (float*)d_out;
  float* outC = outXc + BN * F;
  float* outS = outC + BN * N;
  float* outIM = outS + BN * N;

  char* p = (char*)d_ws;
  auto alloc = [&](size_t bytes) -> void* {
    void* r = (void*)p;
    p += (bytes + 255) / 256 * 256;
    return r;
  };
  float* y = (float*)alloc(BN * 4);
  float* dis = (float*)alloc(BN * 4);
  float* d2 = (float*)alloc(BN * 4);
  float* wsum = (float*)alloc(BN * 4);
  float* alpha = (float*)alloc(BN * 4);
  float* cutA = (float*)alloc(BN * 4);
  int* rowCnt = (int*)alloc(BN * 4);
  int* rowIdx = (int*)alloc(BN * CAP * 4);
  float* rowVal = (float*)alloc(BN * CAP * 4);
  int* colCount = (int*)alloc(BN * 4);
  int* colR = (int*)alloc(BN * CAP * 4);
  float* colV = (float*)alloc(BN * CAP * 4);
  int* colK = (int*)alloc(B * 4);
  int* colIdx = (int*)alloc(BN * 4);
  int* batchDone = (int*)alloc(B * 4);

  int BNi = (int)BN;
  int rowBlocks = (BNi + RPB - 1) / RPB;
  k_prep<<<dim3(rowBlocks), dim3(TPB), 0, stream>>>(x, adj, W, y, rowCnt, rowIdx, rowVal,
                                                    dis, d2, wsum, colCount, colK, batchDone,
                                                    N, F, BNi, B);
  k_alpha_cut<<<dim3(rowBlocks), dim3(TPB), 0, stream>>>(adj, rowCnt, rowIdx, dis, y, bias,
                                                         num_nodes, num_sentences, kptr,
                                                         alpha, cutA, outIM, colK, colIdx,
                                                         batchDone, N, BNi);
  k_srow<<<dim3(rowBlocks), dim3(TPB), 0, stream>>>(adj, rowCnt, rowIdx, rowVal, wsum, d2, cutA,
                                                    outS, colCount, colR, colV, N, BNi);
  k_coarse<<<dim3(BNi), dim3(TPB), 0, stream>>>(adj, x, cutA, rowCnt, rowIdx, rowVal,
                                                colK, colIdx, colCount, colR, colV,
                                                outXc, outC, N, F);
}

// Round 6
// 441.133 us; speedup vs baseline: 1.3689x; 1.3689x over previous
//
#include <hip/hip_runtime.h>
#include <math.h>
#include <limits.h>

#define CAP 64
#define TPB 256
#define RPB 4     // rows per block (one wave each)
#define NMAX 1024

typedef float f4 __attribute__((ext_vector_type(4)));

__device__ inline f4 ntload4(const float* p) { return __builtin_nontemporal_load((const f4*)p); }
__device__ inline void ntstore4(float* p, f4 v) { __builtin_nontemporal_store(v, (f4*)p); }
__device__ inline void ntstore1(float* p, float v) { __builtin_nontemporal_store(v, p); }

__device__ inline float waveSum(float v) {
#pragma unroll
  for (int o = 32; o > 0; o >>= 1) v += __shfl_down(v, o, 64);
  return v;
}

// K1 (fused): per adj row: y-dot, weighted sum, count, compressed nonzero list
// (ballot compaction, no atomics); zeroes colCount/colK. Wave per row.
__global__ void k_prep(const float* __restrict__ x, const float* __restrict__ adj,
                       const float* __restrict__ W, float* __restrict__ y,
                       int* __restrict__ rowCnt, int* __restrict__ rowIdx,
                       float* __restrict__ rowVal, float* __restrict__ dis,
                       float* __restrict__ d2, float* __restrict__ wsum,
                       int* __restrict__ colCount, int* __restrict__ colK,
                       int N, int F, int BN, int B) {
  int wave = threadIdx.x >> 6, lane = threadIdx.x & 63;
  if (blockIdx.x == 0 && threadIdx.x < B) colK[threadIdx.x] = 0;
  int bn = blockIdx.x * RPB + wave;
  if (bn >= BN) return;
  if (lane == 0) colCount[bn] = 0;
  // ---- y = dot(x[bn,:], W) ----
  float p = 0.f;
  if ((F & 3) == 0) {
    const float* xr = x + (size_t)bn * F;
    int f4n = F >> 2;
    for (int i = lane; i < f4n; i += 64) {
      f4 a = *(const f4*)(xr + 4 * i);
      f4 w = *(const f4*)(W + 4 * i);
      p += a.x * w.x + a.y * w.y + a.z * w.z + a.w * w.w;
    }
  } else {
    for (int f = lane; f < F; f += 64) p += x[(size_t)bn * F + f] * W[f];
  }
  float ydot = waveSum(p);
  // ---- adj row scan: sum + ballot-compacted nonzero list ----
  const float* row = adj + (size_t)bn * N;
  size_t lbase = (size_t)bn * CAP;
  unsigned long long below = (1ULL << lane) - 1ULL;
  float ls = 0.f;
  int cnt = 0;
  if ((N & 3) == 0) {
    int n4 = N >> 2;
    for (int q = lane; q < n4; q += 64) {
      f4 v = ntload4(row + 4 * q);
      ls += v.x + v.y + v.z + v.w;
      int j = q << 2;
#pragma unroll
      for (int c = 0; c < 4; c++) {
        float vc = (c == 0) ? v.x : (c == 1) ? v.y : (c == 2) ? v.z : v.w;
        unsigned long long m = __ballot(vc > 0.f);
        if (vc > 0.f) {
          int pos = cnt + __popcll(m & below);
          if (pos < CAP) { rowIdx[lbase + pos] = j + c; rowVal[lbase + pos] = vc; }
        }
        cnt += __popcll(m);
      }
    }
  } else {
    for (int j = lane; j < N; j += 64) {
      float v = row[j];
      ls += v;
      unsigned long long m = __ballot(v > 0.f);
      if (v > 0.f) {
        int pos = cnt + __popcll(m & below);
        if (pos < CAP) { rowIdx[lbase + pos] = j; rowVal[lbase + pos] = v; }
      }
      cnt += __popcll(m);
    }
  }
  float s = waveSum(ls);
  if (lane == 0) {
    y[bn] = ydot;
    rowCnt[bn] = cnt;                          // lane 0 runs max iterations -> full count
    dis[bn] = 1.f / sqrtf((float)(cnt + 1));   // A_hat row sum = count + 1 (self loop)
    wsum[bn] = s;
    d2[bn] = 1.f / sqrtf(fmaxf(s + 1.f, 1.f)); // clip(A2.sum,1)^-0.5
  }
}

// K2: alpha[bn] = sigmoid((dis[n]*(sum dis[m]y[m] + dis[n]y[n]) + b0)^2), -1 if padded
__global__ void k_alpha(const float* __restrict__ adj, const int* __restrict__ rowCnt,
                        const int* __restrict__ rowIdx, const float* __restrict__ dis,
                        const float* __restrict__ y, const float* __restrict__ bptr,
                        const int* __restrict__ num_nodes, float* __restrict__ alpha,
                        int N, int BN) {
  int wave = threadIdx.x >> 6, lane = threadIdx.x & 63;
  int bn = blockIdx.x * RPB + wave;
  if (bn >= BN) return;
  int b = bn / N, n = bn - b * N;
  const float* disB = dis + (size_t)b * N;
  const float* yB = y + (size_t)b * N;
  int cnt = rowCnt[bn];
  float acc = 0.f;
  if (cnt <= CAP) {
    for (int t = lane; t < cnt; t += 64) {
      int j = rowIdx[(size_t)bn * CAP + t];
      acc += disB[j] * yB[j];
    }
  } else {
    const float* row = adj + (size_t)bn * N;
    for (int j = lane; j < N; j += 64)
      if (row[j] > 0.f) acc += disB[j] * yB[j];
  }
  float tot = waveSum(acc);
  if (lane == 0) {
    float dn = dis[bn];
    tot += dn * yB[n];                 // self-loop term
    float z = dn * tot + bptr[0];
    float a;
    if (n < num_nodes[b]) { float z2 = z * z; a = 1.f / (1.f + expf(-z2)); }
    else a = -1.f;
    alpha[bn] = a;
  }
}

// K3: per batch: cut value/node, then cut_alpha, index_mask, nonzero-column list
__global__ void k_cut(const float* __restrict__ alpha, const int* __restrict__ num_sentences,
                      const int* __restrict__ kptr, float* __restrict__ cutA,
                      float* __restrict__ outIM, int* __restrict__ colK,
                      int* __restrict__ colIdx, int N) {
  int b = blockIdx.x;
  const float* aB = alpha + (size_t)b * N;
  __shared__ float s_cutv;
  __shared__ int s_cutn;
  if (threadIdx.x < 64) {
    int lane = threadIdx.x;
    int ns = num_sentences[b];
    int k = kptr[0];
    if (k < 1) k = 1;
    if (k > ns) k = ns;
    unsigned long long used = 0ULL;
    float cv = 0.f; int cn = 0;
    int nslots = (ns + 63) >> 6;
    for (int r = 0; r < k; r++) {
      float bv = -3.4e38f; int bi = INT_MAX;
      for (int s = 0; s < nslots; s++) {
        int idx = lane + (s << 6);
        if (idx < ns && !((used >> s) & 1ULL)) {
          float v = aB[idx];
          if (v > bv || (v == bv && idx < bi)) { bv = v; bi = idx; }
        }
      }
#pragma unroll
      for (int o = 32; o > 0; o >>= 1) {
        float ov = __shfl_down(bv, o, 64);
        int oi = __shfl_down(bi, o, 64);
        if (ov > bv || (ov == bv && oi < bi)) { bv = ov; bi = oi; }
      }
      bv = __shfl(bv, 0, 64);
      bi = __shfl(bi, 0, 64);
      if ((bi & 63) == lane) used |= 1ULL << (bi >> 6);
      cv = bv; cn = bi;
    }
    if (lane == 0) { s_cutv = cv; s_cutn = cn; }
  }
  __syncthreads();
  float cutv = s_cutv;
  int cutn = s_cutn;
  for (int n = threadIdx.x; n < N; n += TPB) {
    float a = aB[n];
    float ca = fmaxf((a + 1e-7f) - cutv, 0.f);
    cutA[(size_t)b * N + n] = ca;
    ntstore1(&outIM[(size_t)b * N + n], (a > cutv || (a == cutv && n <= cutn)) ? 1.f : 0.f);
    if (ca > 0.f) {
      int p = atomicAdd(&colK[b], 1);
      colIdx[(size_t)b * N + p] = n;
    }
  }
}

// K4: S rows — wave per row. Scatter into LDS row, dense nt write, build CSC.
__global__ void k_srow(const float* __restrict__ adj, const int* __restrict__ rowCnt,
                       const int* __restrict__ rowIdx, const float* __restrict__ rowVal,
                       const float* __restrict__ wsum, const float* __restrict__ d2,
                       const float* __restrict__ cutA, float* __restrict__ outS,
                       int* __restrict__ colCount, int* __restrict__ colR,
                       float* __restrict__ colV, int N, int BN) {
  int wave = threadIdx.x >> 6, lane = threadIdx.x & 63;
  int bn = blockIdx.x * RPB + wave;
  bool rowOK = bn < BN;
  __shared__ float srow[RPB][NMAX];
  float* my = srow[wave];
  if (rowOK) {
    f4 z4 = { 0.f, 0.f, 0.f, 0.f };
    int nq = N >> 2;
    for (int q = lane; q < nq; q += 64) *(f4*)&my[4 * q] = z4;
    for (int j = (nq << 2) + lane; j < N; j += 64) my[j] = 0.f;
  }
  if (rowOK && wsum[bn] > 0.f) {
    int b = bn / N, n = bn - b * N;
    int cnt = rowCnt[bn];
    const float* d2B = d2 + (size_t)b * N;
    const float* caB = cutA + (size_t)b * N;
    float d2n = d2[bn];
    if (cnt < CAP) {
      int t = lane;
      int j = -1; float a2 = 0.f;
      if (t < cnt) {
        j = rowIdx[(size_t)bn * CAP + t];
        float v = rowVal[(size_t)bn * CAP + t];
        a2 = v + (j == n ? 1.f : 0.f);
      }
      unsigned long long hasDiag = __ballot(t < cnt && j == n);
      if (t == cnt && hasDiag == 0ULL) { j = n; a2 = 1.f; }
      float sun = 0.f;
      if (j >= 0) {
        float ca = caB[j];
        if (ca > 0.f) sun = d2n * a2 * d2B[j] * ca;
        else j = -1;
      }
      float denom = __shfl(waveSum(sun), 0, 64);
      denom = fmaxf(denom, 1e-12f);
      if (j >= 0) {
        float s = sun / denom;
        my[j] = s;
        int cp = atomicAdd(&colCount[(size_t)b * N + j], 1);
        if (cp < CAP) {
          colR[((size_t)b * N + j) * CAP + cp] = n;
          colV[((size_t)b * N + j) * CAP + cp] = s;
        }
      }
    } else {
      // dense fallback (statistically never taken)
      const float* row = adj + (size_t)bn * N;
      float ls = 0.f;
      for (int j2 = lane; j2 < N; j2 += 64) {
        float v = row[j2];
        bool nz = (v > 0.f) || (j2 == n);
        float a2 = v + (j2 == n ? 1.f : 0.f);
        float ca = caB[j2];
        if (nz && ca > 0.f) ls += d2n * a2 * d2B[j2] * ca;
      }
      float denom = __shfl(waveSum(ls), 0, 64);
      denom = fmaxf(denom, 1e-12f);
      for (int j2 = lane; j2 < N; j2 += 64) {
        float v = row[j2];
        bool nz = (v > 0.f) || (j2 == n);
        float a2 = v + (j2 == n ? 1.f : 0.f);
        float ca = caB[j2];
        if (nz && ca > 0.f) {
          float s = (d2n * a2 * d2B[j2] * ca) / denom;
          my[j2] = s;
          int cp = atomicAdd(&colCount[(size_t)b * N + j2], 1);
          if (cp < CAP) {
            colR[((size_t)b * N + j2) * CAP + cp] = n;
            colV[((size_t)b * N + j2) * CAP + cp] = s;
          }
        }
      }
    }
  }
  if (rowOK) {
    float* dst = outS + (size_t)bn * N;
    if ((N & 3) == 0) {
      int nq = N >> 2;
      for (int q = lane; q < nq; q += 64) ntstore4(dst + 4 * q, *(const f4*)&my[4 * q]);
    } else {
      for (int j = lane; j < N; j += 64) ntstore1(&dst[j], my[j]);
    }
  }
}

// K5: x_c rows (S^T x) and coarse_adj rows (S^T A S with floor) — list-based
__global__ void k_coarse(const float* __restrict__ adj, const float* __restrict__ x,
                         const float* __restrict__ cutA,
                         const int* __restrict__ rowCnt, const int* __restrict__ rowIdx,
                         const float* __restrict__ rowVal,
                         const int* __restrict__ colK, const int* __restrict__ colIdx,
                         const int* __restrict__ colCount, const int* __restrict__ colR,
                         const float* __restrict__ colV,
                         float* __restrict__ outXc, float* __restrict__ outC,
                         int N, int F) {
  int bn = blockIdx.x;
  int b = bn / N;
  float* xcRow = outXc + (size_t)bn * F;
  float* cRow = outC + (size_t)bn * N;
  bool v4N = (N & 3) == 0, v4F = (F & 3) == 0;
  int nq = N >> 2, fq = F >> 2;
  if (cutA[bn] <= 0.f) {
    f4 z4 = { 0.f, 0.f, 0.f, 0.f };
    if (v4F) for (int q = threadIdx.x; q < fq; q += TPB) ntstore4(xcRow + 4 * q, z4);
    else for (int f = threadIdx.x; f < F; f += TPB) ntstore1(&xcRow[f], 0.f);
    if (v4N) for (int q = threadIdx.x; q < nq; q += TPB) ntstore4(cRow + 4 * q, z4);
    else for (int j = threadIdx.x; j < N; j += TPB) ntstore1(&cRow[j], 0.f);
    return;
  }
  __shared__ float T[NMAX];
  __shared__ float crow[NMAX];
  __shared__ int eR[CAP];
  __shared__ float eV[CAP];
  __shared__ int eCnt[CAP];
  int cci = colCount[bn];
  if (cci > CAP) cci = CAP;
  for (int r = threadIdx.x; r < cci; r += TPB) {
    int n_r = colR[(size_t)bn * CAP + r];
    eR[r] = n_r;
    eV[r] = colV[(size_t)bn * CAP + r];
    eCnt[r] = rowCnt[(size_t)b * N + n_r];
  }
  for (int m = threadIdx.x; m < N; m += TPB) { T[m] = 0.f; crow[m] = 0.f; }
  __syncthreads();
  // x_c row: gather over the cci source rows of x
  const float* xB = x + (size_t)b * N * F;
  for (int f = threadIdx.x; f < F; f += TPB) {
    float acc = 0.f;
    for (int r = 0; r < cci; r++) acc += eV[r] * xB[(size_t)eR[r] * F + f];
    ntstore1(&xcRow[f], acc);
  }
  // T = sum_r v_r * adj[n_r,:] via compressed row lists (LDS float atomics)
  for (int idx = threadIdx.x; idx < cci * CAP; idx += TPB) {
    int r = idx >> 6;          // CAP == 64
    int t = idx & (CAP - 1);
    int c = eCnt[r];
    if (c <= CAP && t < c) {
      size_t base = ((size_t)b * N + eR[r]) * CAP;
      atomicAdd(&T[rowIdx[base + t]], eV[r] * rowVal[base + t]);
    }
  }
  // rare fallback: rows whose nonzero count exceeded CAP — stream from adj
  for (int r = 0; r < cci; r++) {
    if (eCnt[r] > CAP) {
      const float* arow = adj + ((size_t)b * N + eR[r]) * N;
      float v = eV[r];
      for (int m = threadIdx.x; m < N; m += TPB) {
        float a = arow[m];
        if (a != 0.f) atomicAdd(&T[m], v * a);
      }
    }
  }
  __syncthreads();
  // C[i,j] for the nonzero columns j via CSC lists
  int K = colK[b];
  for (int jj = threadIdx.x; jj < K; jj += TPB) {
    int j = colIdx[(size_t)b * N + jj];
    int cj = colCount[(size_t)b * N + j];
    if (cj > CAP) cj = CAP;
    const int* jR = colR + ((size_t)b * N + j) * CAP;
    const float* jV = colV + ((size_t)b * N + j) * CAP;
    float cc = 0.f;
    for (int p = 0; p < cj; p++) cc += T[jR[p]] * jV[p];
    crow[j] = floorf(cc * 1e4f) / 1e4f;
  }
  __syncthreads();
  if (v4N) {
    for (int q = threadIdx.x; q < nq; q += TPB) ntstore4(cRow + 4 * q, *(const f4*)&crow[4 * q]);
  } else {
    for (int j = threadIdx.x; j < N; j += TPB) ntstore1(&cRow[j], crow[j]);
  }
}

extern "C" void kernel_launch(void* const* d_in, const int* in_sizes, int n_in,
                              void* d_out, int out_size, void* d_ws, size_t ws_size,
                              hipStream_t stream) {
  const float* x = (const float*)d_in[0];
  const float* adj = (const float*)d_in[1];
  const float* W = (const float*)d_in[2];
  const float* bias = (const float*)d_in[3];
  const int* num_nodes = (const int*)d_in[4];
  const int* num_sentences = (const int*)d_in[5];
  const int* kptr = (const int*)d_in[6];

  int F = in_sizes[2];                             // 256
  int B = in_sizes[4];                             // 32
  int N = (int)(in_sizes[0] / ((long long)B * F)); // 1000
  size_t BN = (size_t)B * N;

  float* outXc = (float*)d_out;
  float* outC = outXc + BN * F;
  float* outS = outC + BN * N;
  float* outIM = outS + BN * N;

  char* p = (char*)d_ws;
  auto alloc = [&](size_t bytes) -> void* {
    void* r = (void*)p;
    p += (bytes + 255) / 256 * 256;
    return r;
  };
  float* y = (float*)alloc(BN * 4);
  float* dis = (float*)alloc(BN * 4);
  float* d2 = (float*)alloc(BN * 4);
  float* wsum = (float*)alloc(BN * 4);
  float* alpha = (float*)alloc(BN * 4);
  float* cutA = (float*)alloc(BN * 4);
  int* rowCnt = (int*)alloc(BN * 4);
  int* rowIdx = (int*)alloc(BN * CAP * 4);
  float* rowVal = (float*)alloc(BN * CAP * 4);
  int* colCount = (int*)alloc(BN * 4);
  int* colR = (int*)alloc(BN * CAP * 4);
  float* colV = (float*)alloc(BN * CAP * 4);
  int* colK = (int*)alloc(B * 4);
  int* colIdx = (int*)alloc(BN * 4);

  int BNi = (int)BN;
  int rowBlocks = (BNi + RPB - 1) / RPB;
  k_prep<<<dim3(rowBlocks), dim3(TPB), 0, stream>>>(x, adj, W, y, rowCnt, rowIdx, rowVal,
                                                    dis, d2, wsum, colCount, colK, N, F, BNi, B);
  k_alpha<<<dim3(rowBlocks), dim3(TPB), 0, stream>>>(adj, rowCnt, rowIdx, dis, y, bias,
                                                     num_nodes, alpha, N, BNi);
  k_cut<<<dim3(B), dim3(TPB), 0, stream>>>(alpha, num_sentences, kptr, cutA, outIM, colK, colIdx, N);
  k_srow<<<dim3(rowBlocks), dim3(TPB), 0, stream>>>(adj, rowCnt, rowIdx, rowVal, wsum, d2, cutA,
                                                    outS, colCount, colR, colV, N, BNi);
  k_coarse<<<dim3(BNi), dim3(TPB), 0, stream>>>(adj, x, cutA, rowCnt, rowIdx, rowVal,
                                                colK, colIdx, colCount, colR, colV,
                                                outXc, outC, N, F);
}